// Round 1
// 116.979 us; speedup vs baseline: 1.0298x; 1.0298x over previous
//
#include <hip/hip_runtime.h>
#include <hip/hip_fp16.h>

// PairwiseMamba: 2304 independent mamba scans (T=1024, d_inner=4, d_state=8).
// R7 = R6 + scan-issue diet. The kernel is VALU-issue-bound (VALUBusy 71%,
// HBM 2.8%, MfmaUtil 0), so this round cuts instructions per scan step:
//  (a) staging re-laid [d][t] so scan reads are t-contiguous per lane:
//      DTDS[d][t] float2{dt, half2(dtx,sz)} row-stride 34 float2 -> one
//      ds_read_b128 per 2 steps; BC[s][t] half2 row-stride 36 uints -> one
//      ds_read_b128 per 4 steps. 12 ds_read insts/4 steps -> 3.
//      Banks hand-checked: DTDS reads banks 4d+8j..+3 (disjoint, s-broadcast),
//      BC reads exactly 32 banks, all writes <=2-way (free). Halves stay 16
//      banks apart (PER_HALF_STRIDE 560 % 32 == 16).
//  (b) v_fma_mix_f32 consumes staged f16 halves directly: b=dtx*B, q=sz*C
//      in 2 insts (was hmul2+2cvt), products now f32 (accuracy headroom).
//  (c) pointwise {xz,zv} packed as v_pk_fma_f32 pairs.
// Launch shape unchanged: one sequence per 256-thr block, wave w half h owns
// segment g=2w+h (128 steps); launch_bounds(256,4) (R5: kills scratch spill).

typedef float v2f __attribute__((ext_vector_type(2)));

#define TT 1024
#define TC 32
#define NSEGS 8
#define SEGLEN (TT / NSEGS)            // 128
#define NCHUNK (SEGLEN / TC)           // 4
#define NUM_PAIRS 36
#define NSEQ 2304

// per-(wave,half) staging layout (float slots):
// DTDS [0,272): [d][t] float2, row stride 34 float2 (t in [0,32), 2 pad)
// BC   [272,560): [s][t] uint half2(B,C), row stride 36 uints (4 pad)
#define DTDS_ROW 34                    // float2 per d-row
#define BC_OFF 272
#define BC_STRIDE 36                   // uints per s-row (16B-aligned rows)
#define PER_HALF_STRIDE 560            // floats; %32==16 -> halves bank-disjoint
#define PER_WAVE (2 * PER_HALF_STRIDE) // 1120 floats
#define STAGE_TOTAL (4 * PER_WAVE)     // 4480 floats = 17920 B

__device__ __forceinline__ float fast_silu(float v) {
    float e = __builtin_amdgcn_exp2f(v * -1.4426950408889634f);
    return v * __builtin_amdgcn_rcpf(1.0f + e);
}
// softplus, direct form: log(1+exp(v)). Safe: |v| <~ 20 here.
__device__ __forceinline__ float fast_softplus(float v) {
    float e = __builtin_amdgcn_exp2f(v * 1.4426950408889634f);
    return __builtin_amdgcn_logf(1.0f + e) * 0.6931471805599453f;
}
__device__ __forceinline__ uint pk_h2(float a, float b) {
    return __builtin_bit_cast(uint, __builtin_amdgcn_cvt_pkrtz(a, b));
}

__global__ __launch_bounds__(256, 4)
void pm_kernel(const float* __restrict__ raw,        // (N,2,T)
               const float* __restrict__ in_proj_w,  // (8,2)
               const float* __restrict__ conv_w,     // (4,2)
               const float* __restrict__ conv_b,     // (4)
               const float* __restrict__ x_proj_w,   // (17,4)
               const float* __restrict__ dt_proj_w,  // (4,1)
               const float* __restrict__ dt_proj_b,  // (4)
               const float* __restrict__ A_log,      // (4,8)
               const float* __restrict__ D_skip,     // (4)
               const float* __restrict__ out_proj_w, // (2,4)
               const float* __restrict__ proj_w,     // (16,2)
               const float* __restrict__ proj_b,     // (16)
               float* __restrict__ out)              // (64,16), pre-zeroed
{
    __shared__ float lds[STAGE_TOTAL];

    const int tid  = threadIdx.x;
    const int wid  = tid >> 6;        // wave 0..3
    const int lane = tid & 63;
    const int half = lane >> 5;
    const int lh   = lane & 31;       // pointwise: t-in-chunk; scan: ds = d*8+s
    const int g    = wid * 2 + half;  // segment 0..7 of THIS block's sequence
    const int n    = blockIdx.x;      // one sequence per block
    const float* rp = raw + (size_t)n * (2 * TT);

    float* hb = lds + wid * PER_WAVE + half * PER_HALF_STRIDE;

    // ---- weights (wave-uniform -> scalarized) ----
    // ipxy{0,1}[d] = {in_proj[d][c], in_proj[4+d][c]} : x-path / z-path pair
    v2f ipxy0[4], ipxy1[4];
#pragma unroll
    for (int d = 0; d < 4; ++d) {
        ipxy0[d] = (v2f){in_proj_w[2*d],     in_proj_w[2*(4+d)]};
        ipxy1[d] = (v2f){in_proj_w[2*d + 1], in_proj_w[2*(4+d) + 1]};
    }
    float cw0[4], cw1[4], cbv[4], dpw[4], dpb[4], Dsk[4], ow0[4], ow1[4], xp0[4];
#pragma unroll
    for (int d = 0; d < 4; ++d) {
        cw0[d] = conv_w[2*d]; cw1[d] = conv_w[2*d+1]; cbv[d] = conv_b[d];
        dpw[d] = dt_proj_w[d]; dpb[d] = dt_proj_b[d];
        Dsk[d] = D_skip[d]; ow0[d] = out_proj_w[d]; ow1[d] = out_proj_w[4+d];
        xp0[d] = x_proj_w[d];
    }
    v2f xbc[8][4];  // {x_proj_w[1+s][d], x_proj_w[9+s][d]}
#pragma unroll
    for (int s = 0; s < 8; ++s)
#pragma unroll
        for (int d = 0; d < 4; ++d)
            xbc[s][d] = (v2f){x_proj_w[4*(1+s) + d], x_proj_w[4*(9+s) + d]};

    const float LOG2E = 1.4426950408889634f;
    // scan-role constants: lane lh -> (d,s)
    const int   d_idx = lh >> 3;
    const int   s_idx = lh & 7;
    const float A2ds  = -__expf(A_log[lh]) * LOG2E;   // a = exp2(dt * A2ds)
    const float owd0  = out_proj_w[d_idx];
    const float owd1  = out_proj_w[4 + d_idx];

    // hoisted scan read pointers (imm offsets inside the loop)
    const float4* dp4 = (const float4*)hb + d_idx * (DTDS_ROW / 2);   // 17 f4/row
    const uint4*  bp4 = (const uint4*)(hb + BC_OFF) + s_idx * (BC_STRIDE / 4);

    // segment-local affine reduction state (per ds lane)
    float A_run = 1.0f, hB = 0.0f, W = 0.0f, S = 0.0f;
    float sacc0 = 0.f, sacc1 = 0.f;                    // skip-term partials
    float zf = 0.0f;                                   // VGPR zero for fma_mix

    const int seg0 = g * SEGLEN;

    // prefetch chunk 0 raw samples (t and t-1, both channels)
    int t0 = seg0 + lh;
    float c0  = rp[t0];
    float c1  = rp[TT + t0];
    float c0m = (t0 > 0) ? rp[t0 - 1]      : 0.0f;     // causal pad at t==0
    float c1m = (t0 > 0) ? rp[TT + t0 - 1] : 0.0f;

    for (int chunk = 0; chunk < NCHUNK; ++chunk) {
        // software prefetch next chunk's raw
        float p0 = 0.f, p1 = 0.f, p0m = 0.f, p1m = 0.f;
        if (chunk + 1 < NCHUNK) {
            int tn = seg0 + (chunk + 1) * TC + lh;     // tn >= 32 -> tn-1 valid
            p0  = rp[tn];       p1  = rp[TT + tn];
            p0m = rp[tn - 1];   p1m = rp[TT + tn - 1];
        }

        // ---- pointwise: this lane handles t = seg0 + chunk*TC + lh ----
        float x[4], sz[4];
        v2f cc0 = (v2f){c0, c0}, cc1 = (v2f){c1, c1};
#pragma unroll
        for (int d = 0; d < 4; ++d) {
            v2f xv = __builtin_elementwise_fma(ipxy1[d], cc1, ipxy0[d] * cc0);
            float xm1 = ipxy0[d].x*c0m + ipxy1[d].x*c1m;
            float v   = xm1*cw0[d] + xv.x*cw1[d] + cbv[d];  // causal conv k=2
            x[d]  = fast_silu(v);
            sz[d] = fast_silu(xv.y);
        }

        float dtin = xp0[0]*x[0] + xp0[1]*x[1] + xp0[2]*x[2] + xp0[3]*x[3];

        v2f bc[8];
#pragma unroll
        for (int s = 0; s < 8; ++s) {
            v2f a = xbc[s][0] * (v2f){x[0], x[0]};
            a = __builtin_elementwise_fma(xbc[s][1], (v2f){x[1], x[1]}, a);
            a = __builtin_elementwise_fma(xbc[s][2], (v2f){x[2], x[2]}, a);
            bc[s] = __builtin_elementwise_fma(xbc[s][3], (v2f){x[3], x[3]}, a);
        }

        float dt[4];
#pragma unroll
        for (int d = 0; d < 4; ++d) {
            dt[d] = fast_softplus(dtin*dpw[d] + dpb[d]);
            float g2 = x[d] * Dsk[d] * sz[d];              // skip term
            sacc0 = fmaf(g2, ow0[d], sacc0);
            sacc1 = fmaf(g2, ow1[d], sacc1);
        }

        // stage: DTDS[d][t] float2 {dt, half2(dtx,sz)} (4x b64, 2-way free),
        // BC[s][t] b32 stride 36 (contiguous lanes, conflict-free)
        float2* dw = (float2*)hb;
#pragma unroll
        for (int d = 0; d < 4; ++d)
            dw[d*DTDS_ROW + lh] = make_float2(
                dt[d], __builtin_bit_cast(float, pk_h2(dt[d]*x[d], sz[d])));
        uint* bcw = (uint*)(hb + BC_OFF) + lh;
#pragma unroll
        for (int s = 0; s < 8; ++s)
            bcw[s * BC_STRIDE] = pk_h2(bc[s].x, bc[s].y);

        // ---- scan: lane owns (d_idx, s_idx); local affine reduction ----
        // (same-wave LDS RAW: per-wave in-order LDS + compiler waitcnt)
        // b = dtx*B, q = sz*C via v_fma_mix_f32 (f16 srcs, f32 product)
#define SCAN_STEP(DTV, DSW, BCW) do {                                        \
            uint _ud = __builtin_bit_cast(uint, (DSW));                      \
            uint _ub = (BCW);                                                \
            float _b, _q;                                                    \
            asm("v_fma_mix_f32 %0, %1, %2, %3 op_sel_hi:[1,1,0]"             \
                : "=v"(_b) : "v"(_ud), "v"(_ub), "v"(zf));                   \
            asm("v_fma_mix_f32 %0, %1, %2, %3 op_sel:[1,1,0] op_sel_hi:[1,1,0]" \
                : "=v"(_q) : "v"(_ud), "v"(_ub), "v"(zf));                   \
            float _a = __builtin_amdgcn_exp2f((DTV) * A2ds);                 \
            A_run *= _a;                   /* running product  П a        */ \
            hB = fmaf(_a, hB, _b);         /* local scan, h_in = 0        */ \
            W  = fmaf(A_run, _q, W);       /* h_in-coupling coefficient   */ \
            S  = fmaf(hB, _q, S);          /* h_in-independent part       */ \
        } while (0)

#pragma unroll
        for (int j = 0; j < TC / 4; ++j) {              // 4 t per iter
            uint4  bq = bp4[j];                         // B,C for t=4j..4j+3
            float4 f0 = dp4[2*j];                       // dt,ds for 4j,4j+1
            float4 f1 = dp4[2*j + 1];                   // dt,ds for 4j+2,4j+3
            SCAN_STEP(f0.x, f0.y, bq.x);
            SCAN_STEP(f0.z, f0.w, bq.y);
            SCAN_STEP(f1.x, f1.y, bq.z);
            SCAN_STEP(f1.z, f1.w, bq.w);
        }
#undef SCAN_STEP

        c0 = p0; c1 = p1; c0m = p0m; c1m = p1m;
    }

    // ---- cross-segment combine (aliases dead staging LDS, post-barrier) ----
    __syncthreads();
    float2* comb = (float2*)lds;                       // 8*32 float2 = 512 floats
    comb[g*32 + lh] = make_float2(A_run, hB);
    __syncthreads();

    // compose the segments before g to get this segment's h_in (g wave-uniform
    // per half; exec-masked loop, max 7 iters)
    float h_in = 0.0f;
#pragma unroll
    for (int gg = 0; gg < NSEGS - 1; ++gg) {
        if (gg < g) {
            float2 abg = comb[gg*32 + lh];
            h_in = fmaf(abg.x, h_in, abg.y);
        }
    }

    float F = fmaf(h_in, W, S);          // this segment's Σ_t h_t q_t for (d,s)
    float tot0 = fmaf(F, owd0, sacc0);
    float tot1 = fmaf(F, owd1, sacc1);
#pragma unroll
    for (int m = 16; m >= 1; m >>= 1) {  // reduce within the 32-lane half
        tot0 += __shfl_xor(tot0, m, 64);
        tot1 += __shfl_xor(tot1, m, 64);
    }
    float* part = lds + 512;             // past comb region
    if (lh == 0) {
        part[g*2]     = tot0;
        part[g*2 + 1] = tot1;
    }
    __syncthreads();

    // wave 0 lanes 0-15: sum segment partials, head projection, mean over pairs
    if (tid < 16) {
        float f0 = 0.f, f1 = 0.f;
#pragma unroll
        for (int gg = 0; gg < NSEGS; ++gg) {
            f0 += part[gg*2];
            f1 += part[gg*2 + 1];
        }
        f0 *= (1.0f / (float)TT);
        f1 *= (1.0f / (float)TT);
        float pv = f0*proj_w[2*tid] + f1*proj_w[2*tid + 1] + proj_b[tid];
        pv = fmaxf(pv, 0.0f);
        atomicAdd(out + (n / NUM_PAIRS) * 16 + tid, pv * (1.0f / NUM_PAIRS));
    }
}

extern "C" void kernel_launch(void* const* d_in, const int* in_sizes, int n_in,
                              void* d_out, int out_size, void* d_ws, size_t ws_size,
                              hipStream_t stream)
{
    const float* raw        = (const float*)d_in[0];
    const float* in_proj_w  = (const float*)d_in[1];
    const float* conv_w     = (const float*)d_in[2];
    const float* conv_b     = (const float*)d_in[3];
    const float* x_proj_w   = (const float*)d_in[4];
    const float* dt_proj_w  = (const float*)d_in[5];
    const float* dt_proj_b  = (const float*)d_in[6];
    const float* A_log      = (const float*)d_in[7];
    const float* D_skip     = (const float*)d_in[8];
    const float* out_proj_w = (const float*)d_in[9];
    const float* proj_w     = (const float*)d_in[10];
    const float* proj_b     = (const float*)d_in[11];

    // d_out is re-poisoned before every timed replay; zero it (atomicAdd sink)
    hipMemsetAsync(d_out, 0, (size_t)out_size * sizeof(float), stream);

    pm_kernel<<<dim3(NSEQ), dim3(256), 0, stream>>>(
        raw, in_proj_w, conv_w, conv_b, x_proj_w, dt_proj_w, dt_proj_b,
        A_log, D_skip, out_proj_w, proj_w, proj_b, (float*)d_out);
}